// Round 1
// baseline (196.216 us; speedup 1.0000x reference)
//
#include <hip/hip_runtime.h>
#include <math.h>

// Problem constants (fixed by the reference).
constexpr int kN  = 250000;
constexpr int kC  = 32;
constexpr int kFC = 16;
constexpr int kFN = 16;
constexpr int kV  = 64;

// One thread per sample. Numerics deliberately mirror the numpy reference:
//  - cat_term: sequential product f=0..15 of cat_probs[c][f][idx_f]
//  - z = (x - m) / s            (IEEE fp32 divide -> bit-exact vs numpy)
//  - lik = (1/(2*pi*s^2)) * expf(-0.5f*(z*z))
//  - num_term: sequential product f=0..15
//  - pred = (class_prob * cat_term) * num_term
//  - argmax with strict '>' ascending c  -> first-max tie-break like jnp.argmax
// The 1/(2*pi*s^2) factor is per-(c,f) constant: precomputed once per block in
// fp32 with the exact same expression -> identical bits, 16x fewer divides.
__global__ __launch_bounds__(256) void nbc_kernel(
    const int*   __restrict__ X_cat,
    const float* __restrict__ X_num,
    const float* __restrict__ class_probs,
    const float* __restrict__ cat_probs,
    const float* __restrict__ means,
    const float* __restrict__ stds,
    int* __restrict__ out)
{
    __shared__ float s_mean[kC * kFN];
    __shared__ float s_std [kC * kFN];
    __shared__ float s_inv [kC * kFN];
    __shared__ float s_cp  [kC];

    const float two_pi = 2.0f * (float)M_PI;  // exact: 2 * fp32(pi)

    for (int i = threadIdx.x; i < kC * kFN; i += blockDim.x) {
        float m = means[i];
        float s = stds[i];
        s_mean[i] = m;
        s_std[i]  = s;
        s_inv[i]  = 1.0f / (two_pi * (s * s));   // same bits as per-sample eval
    }
    if (threadIdx.x < kC) s_cp[threadIdx.x] = class_probs[threadIdx.x];
    __syncthreads();

    const int n = blockIdx.x * 256 + threadIdx.x;
    if (n >= kN) return;

    // Vector-load the 16 categorical indices and 16 numeric features.
    int   idx[kFC];
    float x  [kFN];
    {
        const int4* p4 = reinterpret_cast<const int4*>(X_cat + (size_t)n * kFC);
        int4 a0 = p4[0], a1 = p4[1], a2 = p4[2], a3 = p4[3];
        idx[0]=a0.x;  idx[1]=a0.y;  idx[2]=a0.z;  idx[3]=a0.w;
        idx[4]=a1.x;  idx[5]=a1.y;  idx[6]=a1.z;  idx[7]=a1.w;
        idx[8]=a2.x;  idx[9]=a2.y;  idx[10]=a2.z; idx[11]=a2.w;
        idx[12]=a3.x; idx[13]=a3.y; idx[14]=a3.z; idx[15]=a3.w;

        const float4* q4 = reinterpret_cast<const float4*>(X_num + (size_t)n * kFN);
        float4 b0 = q4[0], b1 = q4[1], b2 = q4[2], b3 = q4[3];
        x[0]=b0.x;  x[1]=b0.y;  x[2]=b0.z;  x[3]=b0.w;
        x[4]=b1.x;  x[5]=b1.y;  x[6]=b1.z;  x[7]=b1.w;
        x[8]=b2.x;  x[9]=b2.y;  x[10]=b2.z; x[11]=b2.w;
        x[12]=b3.x; x[13]=b3.y; x[14]=b3.z; x[15]=b3.w;
    }

    float best  = -INFINITY;
    int   besti = 0;

    #pragma unroll 2
    for (int c = 0; c < kC; ++c) {
        // Categorical term: sequential product, ascending f (numpy order).
        const float* __restrict__ row = cat_probs + (size_t)c * (kFC * kV);
        float cat = row[idx[0]];
        #pragma unroll
        for (int f = 1; f < kFC; ++f) {
            cat *= row[f * kV + idx[f]];
        }

        // Gaussian term: sequential product, ascending f.
        const int base = c * kFN;
        float num;
        #pragma unroll
        for (int f = 0; f < kFN; ++f) {
            float m = s_mean[base + f];
            float s = s_std [base + f];
            float z = (x[f] - m) / s;              // IEEE divide, matches numpy
            float e = expf(-0.5f * (z * z));
            float lik = s_inv[base + f] * e;
            num = (f == 0) ? lik : num * lik;
        }

        float pred = (s_cp[c] * cat) * num;        // ((cp*cat)*num) like reference
        if (pred > best) { best = pred; besti = c; }  // strict > -> first max wins
    }

    out[n] = besti;
}

extern "C" void kernel_launch(void* const* d_in, const int* in_sizes, int n_in,
                              void* d_out, int out_size, void* d_ws, size_t ws_size,
                              hipStream_t stream) {
    const int*   X_cat       = (const int*)  d_in[0];
    const float* X_num       = (const float*)d_in[1];
    const float* class_probs = (const float*)d_in[2];
    const float* cat_probs   = (const float*)d_in[3];
    const float* means       = (const float*)d_in[4];
    const float* stds        = (const float*)d_in[5];
    int* out = (int*)d_out;

    dim3 block(256);
    dim3 grid((kN + 255) / 256);
    hipLaunchKernelGGL(nbc_kernel, grid, block, 0, stream,
                       X_cat, X_num, class_probs, cat_probs, means, stds, out);
}